// Round 12
// baseline (189.393 us; speedup 1.0000x reference)
//
#include <hip/hip_runtime.h>
#include <math.h>

// Sizes (fixed by the problem)
#define BATCH 512   // scan sequence length (original batch dim)
#define E     128
#define DI    256
#define S     256
#define DTR   8
#define KCONV 4
#define JWX   520   // dt(8) + B(256) + C(256)
#define NC    32    // scan chunks
#define TCV   (BATCH / NC)

__device__ __forceinline__ float silu_f(float v) {
    return v / (1.0f + __expf(-v));
}

// ===========================================================================
// kfront: 128 blocks, block g owns batch rows 4g..4g+3.
// Computes conv2d+lin row31 for rows 4g-3..4g+3 (3 neighbor rows RECOMPUTED
// -> no cross-block dependency, no flags; structure verified in R7).
// W_in projection: each loaded low-half float4 feeds all 7 xm dots, each
// high-half float4 feeds 4 zg dots. xm lives only in LDS (global xm deleted).
// conv1d+silu -> xs; W_x streamed once per j, 4 rows per loaded float4;
// delta = softplus(dtin @ W_dt.T + b_dt).
// All per-output accumulation orders identical to R10 -> bit-identical.
// ===========================================================================
__global__ __launch_bounds__(256) void kfront(
    const float* __restrict__ x, const float* __restrict__ conv_w,
    const float* __restrict__ conv_b, const float* __restrict__ lin_w,
    const float* __restrict__ lin_b, const float* __restrict__ W_in,
    const float* __restrict__ c1w, const float* __restrict__ conv1d_b,
    const float* __restrict__ W_x, const float* __restrict__ W_dt,
    const float* __restrict__ b_dt,
    float* __restrict__ zg, float* __restrict__ xs_g,
    float* __restrict__ delta_g, float* __restrict__ Bm,
    float* __restrict__ Cm)
{
    const int tid = threadIdx.x;
    const int g = blockIdx.x, bb = g * 4;
    const int wv = tid >> 6, ln = tid & 63;

    __shared__ float lw[1024];
    __shared__ float red[10][4];
    __shared__ float Tsh[10];
    __shared__ float u[7][E];
    __shared__ float xml[7][DI];
    __shared__ float xs_sh[4][DI];
    __shared__ float dtin[4][8];

    const float4 lv = ((const float4*)(lin_w + 31 * 1024))[tid];
    ((float4*)lw)[tid] = lv;
    __syncthreads();

    // ---- conv2d + lin row 31 for rows bb-3 .. bb+3 (i = 0..6)
    for (int i = 0; i < 7; i++) {
        const int b = bb - 3 + i;
        if (b < 0) continue;               // block-uniform (g==0 only)

        float acc[10];
#pragma unroll
        for (int k = 0; k < 10; k++) acc[k] = 0.0f;

        const float4 xv = ((const float4*)(x + (size_t)b * 1024))[tid];
        const int p0 = tid * 4;
        const int h = p0 >> 5, w0 = p0 & 31;
        const float xa[4] = {xv.x, xv.y, xv.z, xv.w};
#pragma unroll
        for (int k = 0; k < 4; k++) {
            const float xval = xa[k];
            const int w = w0 + k;
#pragma unroll
            for (int ii = 0; ii < 3; ii++) {
                const int hh = h - (ii - 1);
                if (hh < 0 || hh > 31) continue;
#pragma unroll
                for (int j = 0; j < 3; j++) {
                    const int ww = w - (j - 1);
                    if (ww < 0 || ww > 31) continue;
                    acc[ii * 3 + j] += xval * lw[hh * 32 + ww];
                }
            }
        }
        acc[9] = lv.x + lv.y + lv.z + lv.w;

        // multi-value butterfly (same per-value summation tree -> bit-identical)
        float R0, q4;
        {
            float q0, q1, q2, q3;
            {
                const bool b0 = (ln & 1);
                float s_, r_;
                s_ = b0 ? acc[0] : acc[1]; r_ = __shfl_xor(s_, 1, 64);
                q0 = (b0 ? acc[1] : acc[0]) + r_;
                s_ = b0 ? acc[2] : acc[3]; r_ = __shfl_xor(s_, 1, 64);
                q1 = (b0 ? acc[3] : acc[2]) + r_;
                s_ = b0 ? acc[4] : acc[5]; r_ = __shfl_xor(s_, 1, 64);
                q2 = (b0 ? acc[5] : acc[4]) + r_;
                s_ = b0 ? acc[6] : acc[7]; r_ = __shfl_xor(s_, 1, 64);
                q3 = (b0 ? acc[7] : acc[6]) + r_;
                s_ = b0 ? acc[8] : acc[9]; r_ = __shfl_xor(s_, 1, 64);
                q4 = (b0 ? acc[9] : acc[8]) + r_;
            }
            {
                const bool b1 = (ln & 2);
                float s_, r_;
                s_ = b1 ? q0 : q1; r_ = __shfl_xor(s_, 2, 64);
                q0 = (b1 ? q1 : q0) + r_;
                s_ = b1 ? q2 : q3; r_ = __shfl_xor(s_, 2, 64);
                q1 = (b1 ? q3 : q2) + r_;
                q4 += __shfl_xor(q4, 2, 64);
            }
            {
                const bool b2 = (ln & 4);
                const float s_ = b2 ? q0 : q1;
                const float r_ = __shfl_xor(s_, 4, 64);
                R0 = (b2 ? q1 : q0) + r_;
                q4 += __shfl_xor(q4, 4, 64);
            }
            R0 += __shfl_xor(R0, 8, 64);
            R0 += __shfl_xor(R0, 16, 64);
            R0 += __shfl_xor(R0, 32, 64);
            q4 += __shfl_xor(q4, 8, 64);
            q4 += __shfl_xor(q4, 16, 64);
            q4 += __shfl_xor(q4, 32, 64);
        }
        if (ln < 8) red[ln][wv] = R0;
        if (ln < 2) red[8 + ln][wv] = q4;
        __syncthreads();
        if (tid < 10) Tsh[tid] = red[tid][0] + red[tid][1] + red[tid][2] + red[tid][3];
        __syncthreads();

        if (tid < E) {
            const int e = tid;
            float v = lin_b[31] + conv_b[e] * Tsh[9];
#pragma unroll
            for (int k = 0; k < 9; k++) v += conv_w[e * 9 + k] * Tsh[k];
            u[i][e] = v;
        }
        __syncthreads();
    }

    // ---- W_in projection: low float4 feeds all 7 xm dots, high feeds 4 zg
    {
        const float4* w0p = (const float4*)(W_in + (size_t)tid * E);
        const float4* w1p = (const float4*)(W_in + (size_t)(tid + 256) * E);
        float ax[7] = {0.f, 0.f, 0.f, 0.f, 0.f, 0.f, 0.f};
        float az[4] = {0.f, 0.f, 0.f, 0.f};
#pragma unroll 4
        for (int e4 = 0; e4 < E / 4; e4++) {
            const float4 w  = w0p[e4];
            const float4 w2 = w1p[e4];
#pragma unroll
            for (int i = 0; i < 7; i++) {
                ax[i] += u[i][4*e4]*w.x + u[i][4*e4+1]*w.y
                       + u[i][4*e4+2]*w.z + u[i][4*e4+3]*w.w;
            }
#pragma unroll
            for (int r = 0; r < 4; r++) {
                az[r] += u[3 + r][4*e4]*w2.x + u[3 + r][4*e4+1]*w2.y
                       + u[3 + r][4*e4+2]*w2.z + u[3 + r][4*e4+3]*w2.w;
            }
        }
#pragma unroll
        for (int i = 0; i < 7; i++) xml[i][tid] = ax[i];
#pragma unroll
        for (int r = 0; r < 4; r++) zg[(bb + r) * DI + tid] = az[r];
    }
    __syncthreads();

    // ---- conv1d (K=4, causal) + silu -> xs (tap order identical to R10)
    {
        const float4 wc = ((const float4*)c1w)[tid];
        const float cb = conv1d_b[tid];
#pragma unroll
        for (int r = 0; r < 4; r++) {
            const int b = bb + r;
            float a = cb;
            if (b >= 3) a += xml[r + 0][tid] * wc.x;
            if (b >= 2) a += xml[r + 1][tid] * wc.y;
            if (b >= 1) a += xml[r + 2][tid] * wc.z;
            a += xml[r + 3][tid] * wc.w;
            const float s = silu_f(a);
            xs_sh[r][tid] = s;
            xs_g[b * DI + tid] = s;
        }
    }
    __syncthreads();

    // ---- W_x: one row per thread-iteration, all 4 batch rows per float4
    for (int jj = tid; jj < JWX; jj += 256) {
        const float4* wr = (const float4*)(W_x + (size_t)jj * DI);
        const float4* x0 = (const float4*)xs_sh[0];
        const float4* x1 = (const float4*)xs_sh[1];
        const float4* x2 = (const float4*)xs_sh[2];
        const float4* x3 = (const float4*)xs_sh[3];
        float a0 = 0.0f, a1 = 0.0f, a2 = 0.0f, a3 = 0.0f;
#pragma unroll 8
        for (int c4 = 0; c4 < 64; c4++) {
            const float4 w  = wr[c4];
            const float4 v0 = x0[c4];
            const float4 v1 = x1[c4];
            const float4 v2 = x2[c4];
            const float4 v3 = x3[c4];
            a0 += v0.x*w.x; a0 += v0.y*w.y; a0 += v0.z*w.z; a0 += v0.w*w.w;
            a1 += v1.x*w.x; a1 += v1.y*w.y; a1 += v1.z*w.z; a1 += v1.w*w.w;
            a2 += v2.x*w.x; a2 += v2.y*w.y; a2 += v2.z*w.z; a2 += v2.w*w.w;
            a3 += v3.x*w.x; a3 += v3.y*w.y; a3 += v3.z*w.z; a3 += v3.w*w.w;
        }
        const float av[4] = {a0, a1, a2, a3};
        if (jj < DTR) {
#pragma unroll
            for (int r = 0; r < 4; r++) dtin[r][jj] = av[r];
        } else if (jj < DTR + S) {
#pragma unroll
            for (int r = 0; r < 4; r++) Bm[(bb + r) * S + (jj - DTR)] = av[r];
        } else {
#pragma unroll
            for (int r = 0; r < 4; r++) Cm[(bb + r) * S + (jj - DTR - S)] = av[r];
        }
    }
    __syncthreads();

    // ---- delta = softplus(dtin @ W_dt.T + b_dt)
    {
        const int d = tid;
        const float bd = b_dt[d];
        const float4 wd0 = ((const float4*)(W_dt + d * DTR))[0];
        const float4 wd1 = ((const float4*)(W_dt + d * DTR))[1];
#pragma unroll
        for (int r2 = 0; r2 < 4; r2++) {
            float a = bd
                + dtin[r2][0]*wd0.x + dtin[r2][1]*wd0.y + dtin[r2][2]*wd0.z + dtin[r2][3]*wd0.w
                + dtin[r2][4]*wd1.x + dtin[r2][5]*wd1.y + dtin[r2][6]*wd1.z + dtin[r2][7]*wd1.w;
            const float sp = (a > 20.0f) ? a : log1pf(__expf(a));
            delta_g[(bb + r2) * DI + d] = sp;
        }
    }
}

// ---------------------------------------------------------------------------
// K3 chunked scan (NC=32): unchanged (verified bit-identical).
// ---------------------------------------------------------------------------
__global__ __launch_bounds__(256) void k3u_up(
    const float* __restrict__ A_log, const float* __restrict__ delta,
    const float* __restrict__ xs, const float* __restrict__ Bm,
    float* __restrict__ hloc, float* __restrict__ Dchunk)
{
    const int tid = threadIdx.x;
    const int wv = tid >> 6, ln = tid & 63;
    const int d = blockIdx.x * 4 + wv;
    const int c = blockIdx.y;
    const int s0 = ln * 4;
    const int t0 = c * TCV;

    const float4 al = *(const float4*)(A_log + d * S + s0);
    float4 A;
    A.x = -__expf(al.x); A.y = -__expf(al.y);
    A.z = -__expf(al.z); A.w = -__expf(al.w);

    float4 h = make_float4(0.f, 0.f, 0.f, 0.f);
    float cd = 0.0f;
    for (int tb = 0; tb < TCV; tb += 8) {
#pragma unroll
        for (int i = 0; i < 8; i++) {
            const int tt = t0 + tb + i;
            const float dd = delta[tt * DI + d];
            cd += dd;
            const float u = dd * xs[tt * DI + d];
            const float4 B = *(const float4*)(Bm + tt * S + s0);
            h.x = __expf(dd * A.x) * h.x + u * B.x;
            h.y = __expf(dd * A.y) * h.y + u * B.y;
            h.z = __expf(dd * A.z) * h.z + u * B.z;
            h.w = __expf(dd * A.w) * h.w + u * B.w;
        }
    }
    *(float4*)(hloc + ((size_t)(c * DI + d)) * S + s0) = h;
    if (ln == 0) Dchunk[c * DI + d] = cd;
}

__global__ __launch_bounds__(256) void k3d_down(
    const float* __restrict__ A_log, const float* __restrict__ delta,
    const float* __restrict__ xs, const float* __restrict__ Bm,
    const float* __restrict__ Cm, const float* __restrict__ hloc,
    const float* __restrict__ Dchunk, float* __restrict__ y)
{
    const int tid = threadIdx.x;
    const int wv = tid >> 6, ln = tid & 63;
    const int d = blockIdx.x * 4 + wv;
    const int c = (NC - 1) - blockIdx.y;   // heavy carries first
    const int s0 = ln * 4;
    const int t0 = c * TCV;

    const float4 al = *(const float4*)(A_log + d * S + s0);
    float4 A;
    A.x = -__expf(al.x); A.y = -__expf(al.y);
    A.z = -__expf(al.z); A.w = -__expf(al.w);

    float4 h = make_float4(0.f, 0.f, 0.f, 0.f);
    for (int cp = 1; cp <= c; cp++) {
        const float4 hl = *(const float4*)(hloc + ((size_t)((cp - 1) * DI + d)) * S + s0);
        const float Dc = Dchunk[(cp - 1) * DI + d];
        h.x = hl.x + __expf(A.x * Dc) * h.x;
        h.y = hl.y + __expf(A.y * Dc) * h.y;
        h.z = hl.z + __expf(A.z * Dc) * h.z;
        h.w = hl.w + __expf(A.w * Dc) * h.w;
    }

    float pr[8];
    for (int tb = 0; tb < TCV; tb += 8) {
#pragma unroll
        for (int i = 0; i < 8; i++) {
            const int tt = t0 + tb + i;
            const float dd = delta[tt * DI + d];
            const float u = dd * xs[tt * DI + d];
            const float4 B = *(const float4*)(Bm + tt * S + s0);
            const float4 C = *(const float4*)(Cm + tt * S + s0);
            h.x = __expf(dd * A.x) * h.x + u * B.x;
            h.y = __expf(dd * A.y) * h.y + u * B.y;
            h.z = __expf(dd * A.z) * h.z + u * B.z;
            h.w = __expf(dd * A.w) * h.w + u * B.w;
            pr[i] = h.x * C.x + h.y * C.y + h.z * C.z + h.w * C.w;
        }

        float q0, q1, q2, q3;
        {
            const bool b0 = (ln & 1);
            float s_, r_;
            s_ = b0 ? pr[0] : pr[1]; r_ = __shfl_xor(s_, 1, 64);
            q0 = (b0 ? pr[1] : pr[0]) + r_;
            s_ = b0 ? pr[2] : pr[3]; r_ = __shfl_xor(s_, 1, 64);
            q1 = (b0 ? pr[3] : pr[2]) + r_;
            s_ = b0 ? pr[4] : pr[5]; r_ = __shfl_xor(s_, 1, 64);
            q2 = (b0 ? pr[5] : pr[4]) + r_;
            s_ = b0 ? pr[6] : pr[7]; r_ = __shfl_xor(s_, 1, 64);
            q3 = (b0 ? pr[7] : pr[6]) + r_;
        }
        {
            const bool b1 = (ln & 2);
            float s_, r_;
            s_ = b1 ? q0 : q1; r_ = __shfl_xor(s_, 2, 64);
            q0 = (b1 ? q1 : q0) + r_;
            s_ = b1 ? q2 : q3; r_ = __shfl_xor(s_, 2, 64);
            q1 = (b1 ? q3 : q2) + r_;
        }
        {
            const bool b2 = (ln & 4);
            const float s_ = b2 ? q0 : q1;
            const float r_ = __shfl_xor(s_, 4, 64);
            q0 = (b2 ? q1 : q0) + r_;
        }
        q0 += __shfl_xor(q0, 8, 64);
        q0 += __shfl_xor(q0, 16, 64);
        q0 += __shfl_xor(q0, 32, 64);
        if (ln < 8) y[(t0 + tb + ln) * DI + d] = q0;
    }
}

// ---------------------------------------------------------------------------
// K4: unchanged from R10.
// ---------------------------------------------------------------------------
__global__ __launch_bounds__(256) void k4_heads(
    const float* __restrict__ y, const float* __restrict__ xs,
    const float* __restrict__ Dp, const float* __restrict__ zg,
    const float* __restrict__ W_out,
    const float* __restrict__ We, const float* __restrict__ be,
    const float* __restrict__ Wa, const float* __restrict__ ba,
    const float* __restrict__ Wq, const float* __restrict__ bq,
    float* __restrict__ out)
{
    const int bb = blockIdx.x * 2;
    const int tid = threadIdx.x;
    __shared__ float yf[2][DI];
    __shared__ float feat[2][E];

    for (int idx = tid; idx < 2 * DI; idx += 256) {
        const int r = idx >> 8, c = idx & 255;
        const int b = bb + r;
        const float z = zg[b * DI + c];
        yf[r][c] = (y[b * DI + c] + xs[b * DI + c] * Dp[c]) * silu_f(z);
    }
    __syncthreads();

    {
        const int r = tid >> 7, e = tid & 127;
        const float4* wr = (const float4*)(W_out + (size_t)e * DI);
        const float4* yv = (const float4*)yf[r];
        float a = 0.0f;
#pragma unroll 8
        for (int d4 = 0; d4 < 64; d4++) {
            const float4 w = wr[d4];
            const float4 v = yv[d4];
            a += v.x * w.x; a += v.y * w.y; a += v.z * w.z; a += v.w * w.w;
        }
        feat[r][e] = a;
    }
    __syncthreads();

    if (tid < 16) {
        const int r = tid >> 3, hd = tid & 7;
        const int b = bb + r;
        const float* wrow;
        float bias;
        int dst;
        if (hd == 0)      { wrow = We;                 bias = be[0];      dst = b; }
        else if (hd < 4)  { wrow = Wa + (hd - 1) * E;  bias = ba[hd - 1]; dst = 512 + b * 3 + (hd - 1); }
        else              { wrow = Wq + (hd - 4) * E;  bias = bq[hd - 4]; dst = 2048 + b * 4 + (hd - 4); }
        float a = bias;
#pragma unroll 4
        for (int e = 0; e < E; e++) a += feat[r][e] * wrow[e];
        out[dst] = a;
    }
}

// ===========================================================================
extern "C" void kernel_launch(void* const* d_in, const int* in_sizes, int n_in,
                              void* d_out, int out_size, void* d_ws, size_t ws_size,
                              hipStream_t stream)
{
    const float* x        = (const float*)d_in[0];
    const float* conv_w   = (const float*)d_in[1];
    const float* conv_b   = (const float*)d_in[2];
    const float* lin_w    = (const float*)d_in[3];
    const float* lin_b    = (const float*)d_in[4];
    const float* W_in     = (const float*)d_in[5];
    const float* conv1d_w = (const float*)d_in[6];
    const float* conv1d_b = (const float*)d_in[7];
    const float* W_x      = (const float*)d_in[8];
    const float* W_dt     = (const float*)d_in[9];
    const float* b_dt     = (const float*)d_in[10];
    const float* A_log    = (const float*)d_in[11];
    const float* Dp       = (const float*)d_in[12];
    const float* W_out    = (const float*)d_in[13];
    const float* We       = (const float*)d_in[14];
    const float* be       = (const float*)d_in[15];
    const float* Wa       = (const float*)d_in[16];
    const float* ba       = (const float*)d_in[17];
    const float* Wq       = (const float*)d_in[18];
    const float* bq       = (const float*)d_in[19];
    float* out = (float*)d_out;

    float* ws = (float*)d_ws;
    float* zg     = ws;                    // 512*256 each below
    float* xs     = zg     + 512 * 256;
    float* delta  = xs     + 512 * 256;
    float* Bm     = delta  + 512 * 256;
    float* Cm     = Bm     + 512 * 256;
    float* y      = Cm     + 512 * 256;
    float* hloc   = y      + 512 * 256;    // NC*DI*S
    float* Dchunk = hloc   + (size_t)NC * DI * S;   // NC*DI

    kfront<<<128, 256, 0, stream>>>(x, conv_w, conv_b, lin_w, lin_b, W_in,
                                    conv1d_w, conv1d_b, W_x, W_dt, b_dt,
                                    zg, xs, delta, Bm, Cm);
    k3u_up<<<dim3(64, NC), 256, 0, stream>>>(A_log, delta, xs, Bm, hloc, Dchunk);
    k3d_down<<<dim3(64, NC), 256, 0, stream>>>(A_log, delta, xs, Bm, Cm,
                                               hloc, Dchunk, y);
    k4_heads<<<256, 256, 0, stream>>>(y, xs, Dp, zg, W_out, We, be, Wa, ba, Wq, bq, out);
}

// Round 13
// 168.545 us; speedup vs baseline: 1.1237x; 1.1237x over previous
//
#include <hip/hip_runtime.h>
#include <math.h>

// Sizes (fixed by the problem)
#define BATCH 512   // scan sequence length (original batch dim)
#define E     128
#define DI    256
#define S     256
#define DTR   8
#define KCONV 4
#define JWX   520   // dt(8) + B(256) + C(256)
#define NC    32    // scan chunks
#define TCV   (BATCH / NC)

__device__ __forceinline__ float silu_f(float v) {
    return v / (1.0f + __expf(-v));
}

// ---------------------------------------------------------------------------
// kA: 256 blocks x 512 threads. Block handles rows bb=2*bx, bb+1 with the two
// conv2d+lin reductions running IN PARALLEL (half-block per row; each half
// executes exactly R10's 256-thread code -> bit-identical trees).
// W_in projection: one W_in row per thread (rows 0..255 -> xm cols, rows
// 256..511 -> zg cols), dotted against both u[0],u[1] with R10's chain order.
// 8 waves/CU (vs R10's 4) for latency hiding.
// ---------------------------------------------------------------------------
__global__ __launch_bounds__(512) void kA_pre(
    const float* __restrict__ x, const float* __restrict__ conv_w,
    const float* __restrict__ conv_b, const float* __restrict__ lin_w,
    const float* __restrict__ lin_b, const float* __restrict__ W_in,
    float* __restrict__ xm, float* __restrict__ zg)
{
    const int tid = threadIdx.x;
    const int rid = tid >> 8;            // 0 or 1: which batch row this half owns
    const int t2  = tid & 255;           // index within the half
    const int wv2 = t2 >> 6, ln = tid & 63;
    const int bb = blockIdx.x * 2;
    const int b  = bb + rid;

    __shared__ float lw[1024];
    __shared__ float red[2][10][4];
    __shared__ float Tsh[2][10];
    __shared__ float u[2][E];

    const float4 lv = ((const float4*)(lin_w + 31 * 1024))[t2];
    if (tid < 256) ((float4*)lw)[tid] = lv;
    __syncthreads();

    // ---- conv2d + lin row31 for row b (both halves in parallel)
    float acc[10];
#pragma unroll
    for (int k = 0; k < 10; k++) acc[k] = 0.0f;

    const float4 xv = ((const float4*)(x + (size_t)b * 1024))[t2];
    const int p0 = t2 * 4;
    const int h = p0 >> 5, w0 = p0 & 31;
    const float xa[4] = {xv.x, xv.y, xv.z, xv.w};
#pragma unroll
    for (int k = 0; k < 4; k++) {
        const float xval = xa[k];
        const int w = w0 + k;
#pragma unroll
        for (int i = 0; i < 3; i++) {
            const int hh = h - (i - 1);
            if (hh < 0 || hh > 31) continue;
#pragma unroll
            for (int j = 0; j < 3; j++) {
                const int ww = w - (j - 1);
                if (ww < 0 || ww > 31) continue;
                acc[i * 3 + j] += xval * lw[hh * 32 + ww];
            }
        }
    }
    acc[9] = lv.x + lv.y + lv.z + lv.w;

    // multi-value butterfly (per-value summation tree identical to R10)
    float R0, q4;
    {
        float q0, q1, q2, q3;
        {
            const bool b0 = (ln & 1);
            float s_, r_;
            s_ = b0 ? acc[0] : acc[1]; r_ = __shfl_xor(s_, 1, 64);
            q0 = (b0 ? acc[1] : acc[0]) + r_;
            s_ = b0 ? acc[2] : acc[3]; r_ = __shfl_xor(s_, 1, 64);
            q1 = (b0 ? acc[3] : acc[2]) + r_;
            s_ = b0 ? acc[4] : acc[5]; r_ = __shfl_xor(s_, 1, 64);
            q2 = (b0 ? acc[5] : acc[4]) + r_;
            s_ = b0 ? acc[6] : acc[7]; r_ = __shfl_xor(s_, 1, 64);
            q3 = (b0 ? acc[7] : acc[6]) + r_;
            s_ = b0 ? acc[8] : acc[9]; r_ = __shfl_xor(s_, 1, 64);
            q4 = (b0 ? acc[9] : acc[8]) + r_;
        }
        {
            const bool b1 = (ln & 2);
            float s_, r_;
            s_ = b1 ? q0 : q1; r_ = __shfl_xor(s_, 2, 64);
            q0 = (b1 ? q1 : q0) + r_;
            s_ = b1 ? q2 : q3; r_ = __shfl_xor(s_, 2, 64);
            q1 = (b1 ? q3 : q2) + r_;
            q4 += __shfl_xor(q4, 2, 64);
        }
        {
            const bool b2 = (ln & 4);
            const float s_ = b2 ? q0 : q1;
            const float r_ = __shfl_xor(s_, 4, 64);
            R0 = (b2 ? q1 : q0) + r_;
            q4 += __shfl_xor(q4, 4, 64);
        }
        R0 += __shfl_xor(R0, 8, 64);
        R0 += __shfl_xor(R0, 16, 64);
        R0 += __shfl_xor(R0, 32, 64);
        q4 += __shfl_xor(q4, 8, 64);
        q4 += __shfl_xor(q4, 16, 64);
        q4 += __shfl_xor(q4, 32, 64);
    }
    if (ln < 8) red[rid][ln][wv2] = R0;
    if (ln < 2) red[rid][8 + ln][wv2] = q4;
    __syncthreads();
    if (t2 < 10)
        Tsh[rid][t2] = red[rid][t2][0] + red[rid][t2][1] + red[rid][t2][2] + red[rid][t2][3];
    __syncthreads();

    if (t2 < E) {
        const int e = t2;
        float v = lin_b[31] + conv_b[e] * Tsh[rid][9];
#pragma unroll
        for (int k = 0; k < 9; k++) v += conv_w[e * 9 + k] * Tsh[rid][k];
        u[rid][e] = v;
    }
    __syncthreads();

    // ---- W_in projection: one W_in row per thread; chain order = R10
    {
        const float4* wp = (const float4*)(W_in + (size_t)tid * E);
        float a0 = 0.0f, a1 = 0.0f;
#pragma unroll 8
        for (int e4 = 0; e4 < E / 4; e4++) {
            const float4 w = wp[e4];
            a0 += u[0][4*e4]*w.x + u[0][4*e4+1]*w.y + u[0][4*e4+2]*w.z + u[0][4*e4+3]*w.w;
            a1 += u[1][4*e4]*w.x + u[1][4*e4+1]*w.y + u[1][4*e4+2]*w.z + u[1][4*e4+3]*w.w;
        }
        if (tid < 256) {
            xm[(bb + 0) * DI + tid] = a0;
            xm[(bb + 1) * DI + tid] = a1;
        } else {
            zg[(bb + 0) * DI + (tid - 256)] = a0;
            zg[(bb + 1) * DI + (tid - 256)] = a1;
        }
    }
}

// ---------------------------------------------------------------------------
// K2b: grid (128, 2) x 512 threads. bb = bx*4; gy = j-half.
// Phase A: conv1d+silu, 1024 elems strided by 512 (gy==0 stores xs_g).
// Phase B: threads 0..259 each stream ONE W_x row (jj = gy*260+tid) and dot
// all 4 xs rows (body identical to R10 -> bit-identical trees).
// Phase C: delta for 4 rows (gy==0, tid<256).
// 8 waves/CU for latency hiding.
// ---------------------------------------------------------------------------
__global__ __launch_bounds__(512) void k2b_conv_wx(
    const float* __restrict__ xm, const float* __restrict__ c1w,
    const float* __restrict__ conv1d_b, const float* __restrict__ W_x,
    const float* __restrict__ W_dt, const float* __restrict__ b_dt,
    float* __restrict__ xs_g, float* __restrict__ delta_g,
    float* __restrict__ Bm, float* __restrict__ Cm)
{
    const int bb = blockIdx.x * 4;
    const int gy = blockIdx.y;           // 0,1 -> j in [gy*260, gy*260+260)
    const int tid = threadIdx.x;
    __shared__ float xs_sh[4][DI];
    __shared__ float dtin[4][8];

    // phase A: conv1d + silu (recomputed per gy, stored once)
    for (int idx = tid; idx < 4 * DI; idx += 512) {
        const int r = idx >> 8, c = idx & 255;
        const int b = bb + r;
        const float4 wc = ((const float4*)c1w)[c];
        float a = conv1d_b[c];
        if (b >= 3) a += xm[(b - 3) * DI + c] * wc.x;
        if (b >= 2) a += xm[(b - 2) * DI + c] * wc.y;
        if (b >= 1) a += xm[(b - 1) * DI + c] * wc.z;
        a += xm[b * DI + c] * wc.w;
        const float s = silu_f(a);
        xs_sh[r][c] = s;
        if (gy == 0) xs_g[b * DI + c] = s;
    }
    __syncthreads();

    // phase B: one W_x row per thread, all 4 batch rows per loaded float4
    if (tid < 260) {
        const int jj = gy * 260 + tid;               // < 520 always
        const float4* wr = (const float4*)(W_x + (size_t)jj * DI);
        const float4* x0 = (const float4*)xs_sh[0];
        const float4* x1 = (const float4*)xs_sh[1];
        const float4* x2 = (const float4*)xs_sh[2];
        const float4* x3 = (const float4*)xs_sh[3];
        float a0 = 0.0f, a1 = 0.0f, a2 = 0.0f, a3 = 0.0f;
#pragma unroll 8
        for (int c4 = 0; c4 < 64; c4++) {
            const float4 w  = wr[c4];
            const float4 v0 = x0[c4];
            const float4 v1 = x1[c4];
            const float4 v2 = x2[c4];
            const float4 v3 = x3[c4];
            a0 += v0.x*w.x; a0 += v0.y*w.y; a0 += v0.z*w.z; a0 += v0.w*w.w;
            a1 += v1.x*w.x; a1 += v1.y*w.y; a1 += v1.z*w.z; a1 += v1.w*w.w;
            a2 += v2.x*w.x; a2 += v2.y*w.y; a2 += v2.z*w.z; a2 += v2.w*w.w;
            a3 += v3.x*w.x; a3 += v3.y*w.y; a3 += v3.z*w.z; a3 += v3.w*w.w;
        }
        const float av[4] = {a0, a1, a2, a3};
        if (jj < DTR) {
#pragma unroll
            for (int r = 0; r < 4; r++) dtin[r][jj] = av[r];
        } else if (jj < DTR + S) {
#pragma unroll
            for (int r = 0; r < 4; r++) Bm[(bb + r) * S + (jj - DTR)] = av[r];
        } else {
#pragma unroll
            for (int r = 0; r < 4; r++) Cm[(bb + r) * S + (jj - DTR - S)] = av[r];
        }
    }
    __syncthreads();

    // phase C: delta = softplus(dtin @ W_dt.T + b_dt), 4 rows (gy==0 only)
    if (gy == 0 && tid < 256) {
        const int d = tid;
        const float bd = b_dt[d];
        const float4 wd0 = ((const float4*)(W_dt + d * DTR))[0];
        const float4 wd1 = ((const float4*)(W_dt + d * DTR))[1];
#pragma unroll
        for (int r2 = 0; r2 < 4; r2++) {
            float a = bd
                + dtin[r2][0]*wd0.x + dtin[r2][1]*wd0.y + dtin[r2][2]*wd0.z + dtin[r2][3]*wd0.w
                + dtin[r2][4]*wd1.x + dtin[r2][5]*wd1.y + dtin[r2][6]*wd1.z + dtin[r2][7]*wd1.w;
            const float sp = (a > 20.0f) ? a : log1pf(__expf(a));
            delta_g[(bb + r2) * DI + d] = sp;
        }
    }
}

// ---------------------------------------------------------------------------
// K3 chunked scan (NC=32): bodies unchanged (verified bit-identical).
// k3u launched for chunks 0..30 only (chunk 31's summaries are never read).
// ---------------------------------------------------------------------------
__global__ __launch_bounds__(256) void k3u_up(
    const float* __restrict__ A_log, const float* __restrict__ delta,
    const float* __restrict__ xs, const float* __restrict__ Bm,
    float* __restrict__ hloc, float* __restrict__ Dchunk)
{
    const int tid = threadIdx.x;
    const int wv = tid >> 6, ln = tid & 63;
    const int d = blockIdx.x * 4 + wv;
    const int c = blockIdx.y;
    const int s0 = ln * 4;
    const int t0 = c * TCV;

    const float4 al = *(const float4*)(A_log + d * S + s0);
    float4 A;
    A.x = -__expf(al.x); A.y = -__expf(al.y);
    A.z = -__expf(al.z); A.w = -__expf(al.w);

    float4 h = make_float4(0.f, 0.f, 0.f, 0.f);
    float cd = 0.0f;
    for (int tb = 0; tb < TCV; tb += 8) {
#pragma unroll
        for (int i = 0; i < 8; i++) {
            const int tt = t0 + tb + i;
            const float dd = delta[tt * DI + d];
            cd += dd;
            const float u = dd * xs[tt * DI + d];
            const float4 B = *(const float4*)(Bm + tt * S + s0);
            h.x = __expf(dd * A.x) * h.x + u * B.x;
            h.y = __expf(dd * A.y) * h.y + u * B.y;
            h.z = __expf(dd * A.z) * h.z + u * B.z;
            h.w = __expf(dd * A.w) * h.w + u * B.w;
        }
    }
    *(float4*)(hloc + ((size_t)(c * DI + d)) * S + s0) = h;
    if (ln == 0) Dchunk[c * DI + d] = cd;
}

__global__ __launch_bounds__(256) void k3d_down(
    const float* __restrict__ A_log, const float* __restrict__ delta,
    const float* __restrict__ xs, const float* __restrict__ Bm,
    const float* __restrict__ Cm, const float* __restrict__ hloc,
    const float* __restrict__ Dchunk, float* __restrict__ y)
{
    const int tid = threadIdx.x;
    const int wv = tid >> 6, ln = tid & 63;
    const int d = blockIdx.x * 4 + wv;
    const int c = (NC - 1) - blockIdx.y;   // heavy carries first
    const int s0 = ln * 4;
    const int t0 = c * TCV;

    const float4 al = *(const float4*)(A_log + d * S + s0);
    float4 A;
    A.x = -__expf(al.x); A.y = -__expf(al.y);
    A.z = -__expf(al.z); A.w = -__expf(al.w);

    float4 h = make_float4(0.f, 0.f, 0.f, 0.f);
    for (int cp = 1; cp <= c; cp++) {
        const float4 hl = *(const float4*)(hloc + ((size_t)((cp - 1) * DI + d)) * S + s0);
        const float Dc = Dchunk[(cp - 1) * DI + d];
        h.x = hl.x + __expf(A.x * Dc) * h.x;
        h.y = hl.y + __expf(A.y * Dc) * h.y;
        h.z = hl.z + __expf(A.z * Dc) * h.z;
        h.w = hl.w + __expf(A.w * Dc) * h.w;
    }

    float pr[8];
    for (int tb = 0; tb < TCV; tb += 8) {
#pragma unroll
        for (int i = 0; i < 8; i++) {
            const int tt = t0 + tb + i;
            const float dd = delta[tt * DI + d];
            const float u = dd * xs[tt * DI + d];
            const float4 B = *(const float4*)(Bm + tt * S + s0);
            const float4 C = *(const float4*)(Cm + tt * S + s0);
            h.x = __expf(dd * A.x) * h.x + u * B.x;
            h.y = __expf(dd * A.y) * h.y + u * B.y;
            h.z = __expf(dd * A.z) * h.z + u * B.z;
            h.w = __expf(dd * A.w) * h.w + u * B.w;
            pr[i] = h.x * C.x + h.y * C.y + h.z * C.z + h.w * C.w;
        }

        float q0, q1, q2, q3;
        {
            const bool b0 = (ln & 1);
            float s_, r_;
            s_ = b0 ? pr[0] : pr[1]; r_ = __shfl_xor(s_, 1, 64);
            q0 = (b0 ? pr[1] : pr[0]) + r_;
            s_ = b0 ? pr[2] : pr[3]; r_ = __shfl_xor(s_, 1, 64);
            q1 = (b0 ? pr[3] : pr[2]) + r_;
            s_ = b0 ? pr[4] : pr[5]; r_ = __shfl_xor(s_, 1, 64);
            q2 = (b0 ? pr[5] : pr[4]) + r_;
            s_ = b0 ? pr[6] : pr[7]; r_ = __shfl_xor(s_, 1, 64);
            q3 = (b0 ? pr[7] : pr[6]) + r_;
        }
        {
            const bool b1 = (ln & 2);
            float s_, r_;
            s_ = b1 ? q0 : q1; r_ = __shfl_xor(s_, 2, 64);
            q0 = (b1 ? q1 : q0) + r_;
            s_ = b1 ? q2 : q3; r_ = __shfl_xor(s_, 2, 64);
            q1 = (b1 ? q3 : q2) + r_;
        }
        {
            const bool b2 = (ln & 4);
            const float s_ = b2 ? q0 : q1;
            const float r_ = __shfl_xor(s_, 4, 64);
            q0 = (b2 ? q1 : q0) + r_;
        }
        q0 += __shfl_xor(q0, 8, 64);
        q0 += __shfl_xor(q0, 16, 64);
        q0 += __shfl_xor(q0, 32, 64);
        if (ln < 8) y[(t0 + tb + ln) * DI + d] = q0;
    }
}

// ---------------------------------------------------------------------------
// K4: unchanged from R10.
// ---------------------------------------------------------------------------
__global__ __launch_bounds__(256) void k4_heads(
    const float* __restrict__ y, const float* __restrict__ xs,
    const float* __restrict__ Dp, const float* __restrict__ zg,
    const float* __restrict__ W_out,
    const float* __restrict__ We, const float* __restrict__ be,
    const float* __restrict__ Wa, const float* __restrict__ ba,
    const float* __restrict__ Wq, const float* __restrict__ bq,
    float* __restrict__ out)
{
    const int bb = blockIdx.x * 2;
    const int tid = threadIdx.x;
    __shared__ float yf[2][DI];
    __shared__ float feat[2][E];

    for (int idx = tid; idx < 2 * DI; idx += 256) {
        const int r = idx >> 8, c = idx & 255;
        const int b = bb + r;
        const float z = zg[b * DI + c];
        yf[r][c] = (y[b * DI + c] + xs[b * DI + c] * Dp[c]) * silu_f(z);
    }
    __syncthreads();

    {
        const int r = tid >> 7, e = tid & 127;
        const float4* wr = (const float4*)(W_out + (size_t)e * DI);
        const float4* yv = (const float4*)yf[r];
        float a = 0.0f;
#pragma unroll 8
        for (int d4 = 0; d4 < 64; d4++) {
            const float4 w = wr[d4];
            const float4 v = yv[d4];
            a += v.x * w.x; a += v.y * w.y; a += v.z * w.z; a += v.w * w.w;
        }
        feat[r][e] = a;
    }
    __syncthreads();

    if (tid < 16) {
        const int r = tid >> 3, hd = tid & 7;
        const int b = bb + r;
        const float* wrow;
        float bias;
        int dst;
        if (hd == 0)      { wrow = We;                 bias = be[0];      dst = b; }
        else if (hd < 4)  { wrow = Wa + (hd - 1) * E;  bias = ba[hd - 1]; dst = 512 + b * 3 + (hd - 1); }
        else              { wrow = Wq + (hd - 4) * E;  bias = bq[hd - 4]; dst = 2048 + b * 4 + (hd - 4); }
        float a = bias;
#pragma unroll 4
        for (int e = 0; e < E; e++) a += feat[r][e] * wrow[e];
        out[dst] = a;
    }
}

// ===========================================================================
extern "C" void kernel_launch(void* const* d_in, const int* in_sizes, int n_in,
                              void* d_out, int out_size, void* d_ws, size_t ws_size,
                              hipStream_t stream)
{
    const float* x        = (const float*)d_in[0];
    const float* conv_w   = (const float*)d_in[1];
    const float* conv_b   = (const float*)d_in[2];
    const float* lin_w    = (const float*)d_in[3];
    const float* lin_b    = (const float*)d_in[4];
    const float* W_in     = (const float*)d_in[5];
    const float* conv1d_w = (const float*)d_in[6];
    const float* conv1d_b = (const float*)d_in[7];
    const float* W_x      = (const float*)d_in[8];
    const float* W_dt     = (const float*)d_in[9];
    const float* b_dt     = (const float*)d_in[10];
    const float* A_log    = (const float*)d_in[11];
    const float* Dp       = (const float*)d_in[12];
    const float* W_out    = (const float*)d_in[13];
    const float* We       = (const float*)d_in[14];
    const float* be       = (const float*)d_in[15];
    const float* Wa       = (const float*)d_in[16];
    const float* ba       = (const float*)d_in[17];
    const float* Wq       = (const float*)d_in[18];
    const float* bq       = (const float*)d_in[19];
    float* out = (float*)d_out;

    float* ws = (float*)d_ws;
    float* xm     = ws;                    // 512*256 each below
    float* zg     = xm     + 512 * 256;
    float* xs     = zg     + 512 * 256;
    float* delta  = xs     + 512 * 256;
    float* Bm     = delta  + 512 * 256;
    float* Cm     = Bm     + 512 * 256;
    float* y      = Cm     + 512 * 256;
    float* hloc   = y      + 512 * 256;    // NC*DI*S
    float* Dchunk = hloc   + (size_t)NC * DI * S;   // NC*DI

    kA_pre<<<256, 512, 0, stream>>>(x, conv_w, conv_b, lin_w, lin_b, W_in,
                                    xm, zg);
    k2b_conv_wx<<<dim3(128, 2), 512, 0, stream>>>(xm, conv1d_w, conv1d_b, W_x,
                                                  W_dt, b_dt, xs, delta, Bm, Cm);
    k3u_up<<<dim3(64, NC - 1), 256, 0, stream>>>(A_log, delta, xs, Bm, hloc, Dchunk);
    k3d_down<<<dim3(64, NC), 256, 0, stream>>>(A_log, delta, xs, Bm, Cm,
                                               hloc, Dchunk, y);
    k4_heads<<<256, 256, 0, stream>>>(y, xs, Dp, zg, W_out, We, be, Wa, ba, Wq, bq, out);
}

// Round 14
// 167.613 us; speedup vs baseline: 1.1299x; 1.0056x over previous
//
#include <hip/hip_runtime.h>
#include <math.h>

// Sizes (fixed by the problem)
#define BATCH 512   // scan sequence length (original batch dim)
#define E     128
#define DI    256
#define S     256
#define DTR   8
#define KCONV 4
#define JWX   520   // dt(8) + B(256) + C(256)
#define NC    32    // scan chunks
#define TCV   (BATCH / NC)

__device__ __forceinline__ float silu_f(float v) {
    return v / (1.0f + __expf(-v));
}

// ---------------------------------------------------------------------------
// kA: 256 blocks x 512 threads (verified R13). Two conv2d+lin reductions in
// parallel (half-block per row, R10-identical trees); W_in projection one
// row per thread.
// ---------------------------------------------------------------------------
__global__ __launch_bounds__(512) void kA_pre(
    const float* __restrict__ x, const float* __restrict__ conv_w,
    const float* __restrict__ conv_b, const float* __restrict__ lin_w,
    const float* __restrict__ lin_b, const float* __restrict__ W_in,
    float* __restrict__ xm, float* __restrict__ zg)
{
    const int tid = threadIdx.x;
    const int rid = tid >> 8;            // 0 or 1: which batch row this half owns
    const int t2  = tid & 255;           // index within the half
    const int wv2 = t2 >> 6, ln = tid & 63;
    const int bb = blockIdx.x * 2;
    const int b  = bb + rid;

    __shared__ float lw[1024];
    __shared__ float red[2][10][4];
    __shared__ float Tsh[2][10];
    __shared__ float u[2][E];

    const float4 lv = ((const float4*)(lin_w + 31 * 1024))[t2];
    if (tid < 256) ((float4*)lw)[tid] = lv;
    __syncthreads();

    // ---- conv2d + lin row31 for row b (both halves in parallel)
    float acc[10];
#pragma unroll
    for (int k = 0; k < 10; k++) acc[k] = 0.0f;

    const float4 xv = ((const float4*)(x + (size_t)b * 1024))[t2];
    const int p0 = t2 * 4;
    const int h = p0 >> 5, w0 = p0 & 31;
    const float xa[4] = {xv.x, xv.y, xv.z, xv.w};
#pragma unroll
    for (int k = 0; k < 4; k++) {
        const float xval = xa[k];
        const int w = w0 + k;
#pragma unroll
        for (int i = 0; i < 3; i++) {
            const int hh = h - (i - 1);
            if (hh < 0 || hh > 31) continue;
#pragma unroll
            for (int j = 0; j < 3; j++) {
                const int ww = w - (j - 1);
                if (ww < 0 || ww > 31) continue;
                acc[i * 3 + j] += xval * lw[hh * 32 + ww];
            }
        }
    }
    acc[9] = lv.x + lv.y + lv.z + lv.w;

    // multi-value butterfly (per-value summation tree identical to R10)
    float R0, q4;
    {
        float q0, q1, q2, q3;
        {
            const bool b0 = (ln & 1);
            float s_, r_;
            s_ = b0 ? acc[0] : acc[1]; r_ = __shfl_xor(s_, 1, 64);
            q0 = (b0 ? acc[1] : acc[0]) + r_;
            s_ = b0 ? acc[2] : acc[3]; r_ = __shfl_xor(s_, 1, 64);
            q1 = (b0 ? acc[3] : acc[2]) + r_;
            s_ = b0 ? acc[4] : acc[5]; r_ = __shfl_xor(s_, 1, 64);
            q2 = (b0 ? acc[5] : acc[4]) + r_;
            s_ = b0 ? acc[6] : acc[7]; r_ = __shfl_xor(s_, 1, 64);
            q3 = (b0 ? acc[7] : acc[6]) + r_;
            s_ = b0 ? acc[8] : acc[9]; r_ = __shfl_xor(s_, 1, 64);
            q4 = (b0 ? acc[9] : acc[8]) + r_;
        }
        {
            const bool b1 = (ln & 2);
            float s_, r_;
            s_ = b1 ? q0 : q1; r_ = __shfl_xor(s_, 2, 64);
            q0 = (b1 ? q1 : q0) + r_;
            s_ = b1 ? q2 : q3; r_ = __shfl_xor(s_, 2, 64);
            q1 = (b1 ? q3 : q2) + r_;
            q4 += __shfl_xor(q4, 2, 64);
        }
        {
            const bool b2 = (ln & 4);
            const float s_ = b2 ? q0 : q1;
            const float r_ = __shfl_xor(s_, 4, 64);
            R0 = (b2 ? q1 : q0) + r_;
            q4 += __shfl_xor(q4, 4, 64);
        }
        R0 += __shfl_xor(R0, 8, 64);
        R0 += __shfl_xor(R0, 16, 64);
        R0 += __shfl_xor(R0, 32, 64);
        q4 += __shfl_xor(q4, 8, 64);
        q4 += __shfl_xor(q4, 16, 64);
        q4 += __shfl_xor(q4, 32, 64);
    }
    if (ln < 8) red[rid][ln][wv2] = R0;
    if (ln < 2) red[rid][8 + ln][wv2] = q4;
    __syncthreads();
    if (t2 < 10)
        Tsh[rid][t2] = red[rid][t2][0] + red[rid][t2][1] + red[rid][t2][2] + red[rid][t2][3];
    __syncthreads();

    if (t2 < E) {
        const int e = t2;
        float v = lin_b[31] + conv_b[e] * Tsh[rid][9];
#pragma unroll
        for (int k = 0; k < 9; k++) v += conv_w[e * 9 + k] * Tsh[rid][k];
        u[rid][e] = v;
    }
    __syncthreads();

    // ---- W_in projection: one W_in row per thread; chain order = R10
    {
        const float4* wp = (const float4*)(W_in + (size_t)tid * E);
        float a0 = 0.0f, a1 = 0.0f;
#pragma unroll 8
        for (int e4 = 0; e4 < E / 4; e4++) {
            const float4 w = wp[e4];
            a0 += u[0][4*e4]*w.x + u[0][4*e4+1]*w.y + u[0][4*e4+2]*w.z + u[0][4*e4+3]*w.w;
            a1 += u[1][4*e4]*w.x + u[1][4*e4+1]*w.y + u[1][4*e4+2]*w.z + u[1][4*e4+3]*w.w;
        }
        if (tid < 256) {
            xm[(bb + 0) * DI + tid] = a0;
            xm[(bb + 1) * DI + tid] = a1;
        } else {
            zg[(bb + 0) * DI + (tid - 256)] = a0;
            zg[(bb + 1) * DI + (tid - 256)] = a1;
        }
    }
}

// ---------------------------------------------------------------------------
// K2b: grid (128, 2) x 512 threads. Phase B SPLIT-K: each j handled by TWO
// threads (c-halves 0..127 / 128..255); partials combined in LDS as lo+hi.
// All 512 threads active in the heavy loop. 4-j tail (jl 256..259) done by
// threads 0..7 in a second mini-pass.
// ---------------------------------------------------------------------------
__global__ __launch_bounds__(512) void k2b_conv_wx(
    const float* __restrict__ xm, const float* __restrict__ c1w,
    const float* __restrict__ conv1d_b, const float* __restrict__ W_x,
    const float* __restrict__ W_dt, const float* __restrict__ b_dt,
    float* __restrict__ xs_g, float* __restrict__ delta_g,
    float* __restrict__ Bm, float* __restrict__ Cm)
{
    const int bb = blockIdx.x * 4;
    const int gy = blockIdx.y;           // 0,1 -> j in [gy*260, gy*260+260)
    const int tid = threadIdx.x;
    __shared__ float xs_sh[4][DI];
    __shared__ float part[260][4][2];    // [jl][r][half]
    __shared__ float dtin[4][8];

    // phase A: conv1d + silu (recomputed per gy, stored once)
    for (int idx = tid; idx < 4 * DI; idx += 512) {
        const int r = idx >> 8, c = idx & 255;
        const int b = bb + r;
        const float4 wc = ((const float4*)c1w)[c];
        float a = conv1d_b[c];
        if (b >= 3) a += xm[(b - 3) * DI + c] * wc.x;
        if (b >= 2) a += xm[(b - 2) * DI + c] * wc.y;
        if (b >= 1) a += xm[(b - 1) * DI + c] * wc.z;
        a += xm[b * DI + c] * wc.w;
        const float s = silu_f(a);
        xs_sh[r][c] = s;
        if (gy == 0) xs_g[b * DI + c] = s;
    }
    __syncthreads();

    // phase B: split-K. Pass 1: jl = tid>>1 (0..255); pass 2: jl 256..259.
    for (int pass = 0; pass < 2; pass++) {
        int jl, hf;
        if (pass == 0) { jl = tid >> 1;        hf = tid & 1; }
        else           { jl = 256 + (tid >> 1); hf = tid & 1; if (tid >= 8) break; }
        const int jj = gy * 260 + jl;
        const float4* wr = (const float4*)(W_x + (size_t)jj * DI) + hf * 32;
        const float4* x0 = (const float4*)xs_sh[0] + hf * 32;
        const float4* x1 = (const float4*)xs_sh[1] + hf * 32;
        const float4* x2 = (const float4*)xs_sh[2] + hf * 32;
        const float4* x3 = (const float4*)xs_sh[3] + hf * 32;
        float a0 = 0.0f, a1 = 0.0f, a2 = 0.0f, a3 = 0.0f;
#pragma unroll 8
        for (int c4 = 0; c4 < 32; c4++) {
            const float4 w  = wr[c4];
            const float4 v0 = x0[c4];
            const float4 v1 = x1[c4];
            const float4 v2 = x2[c4];
            const float4 v3 = x3[c4];
            a0 += v0.x*w.x; a0 += v0.y*w.y; a0 += v0.z*w.z; a0 += v0.w*w.w;
            a1 += v1.x*w.x; a1 += v1.y*w.y; a1 += v1.z*w.z; a1 += v1.w*w.w;
            a2 += v2.x*w.x; a2 += v2.y*w.y; a2 += v2.z*w.z; a2 += v2.w*w.w;
            a3 += v3.x*w.x; a3 += v3.y*w.y; a3 += v3.z*w.z; a3 += v3.w*w.w;
        }
        part[jl][0][hf] = a0;
        part[jl][1][hf] = a1;
        part[jl][2][hf] = a2;
        part[jl][3][hf] = a3;
    }
    __syncthreads();

    // combine halves (lo + hi) and scatter
    for (int jl = tid; jl < 260; jl += 512) {
        const int jj = gy * 260 + jl;
        float av[4];
#pragma unroll
        for (int r = 0; r < 4; r++) av[r] = part[jl][r][0] + part[jl][r][1];
        if (jj < DTR) {
#pragma unroll
            for (int r = 0; r < 4; r++) dtin[r][jj] = av[r];
        } else if (jj < DTR + S) {
#pragma unroll
            for (int r = 0; r < 4; r++) Bm[(bb + r) * S + (jj - DTR)] = av[r];
        } else {
#pragma unroll
            for (int r = 0; r < 4; r++) Cm[(bb + r) * S + (jj - DTR - S)] = av[r];
        }
    }
    __syncthreads();

    // phase C: delta = softplus(dtin @ W_dt.T + b_dt), 4 rows (gy==0 only)
    if (gy == 0 && tid < 256) {
        const int d = tid;
        const float bd = b_dt[d];
        const float4 wd0 = ((const float4*)(W_dt + d * DTR))[0];
        const float4 wd1 = ((const float4*)(W_dt + d * DTR))[1];
#pragma unroll
        for (int r2 = 0; r2 < 4; r2++) {
            float a = bd
                + dtin[r2][0]*wd0.x + dtin[r2][1]*wd0.y + dtin[r2][2]*wd0.z + dtin[r2][3]*wd0.w
                + dtin[r2][4]*wd1.x + dtin[r2][5]*wd1.y + dtin[r2][6]*wd1.z + dtin[r2][7]*wd1.w;
            const float sp = (a > 20.0f) ? a : log1pf(__expf(a));
            delta_g[(bb + r2) * DI + d] = sp;
        }
    }
}

// ---------------------------------------------------------------------------
// K3 chunked scan (NC=32): bodies unchanged (verified bit-identical).
// k3u launched for chunks 0..30 only (chunk 31's summaries are never read).
// ---------------------------------------------------------------------------
__global__ __launch_bounds__(256) void k3u_up(
    const float* __restrict__ A_log, const float* __restrict__ delta,
    const float* __restrict__ xs, const float* __restrict__ Bm,
    float* __restrict__ hloc, float* __restrict__ Dchunk)
{
    const int tid = threadIdx.x;
    const int wv = tid >> 6, ln = tid & 63;
    const int d = blockIdx.x * 4 + wv;
    const int c = blockIdx.y;
    const int s0 = ln * 4;
    const int t0 = c * TCV;

    const float4 al = *(const float4*)(A_log + d * S + s0);
    float4 A;
    A.x = -__expf(al.x); A.y = -__expf(al.y);
    A.z = -__expf(al.z); A.w = -__expf(al.w);

    float4 h = make_float4(0.f, 0.f, 0.f, 0.f);
    float cd = 0.0f;
    for (int tb = 0; tb < TCV; tb += 8) {
#pragma unroll
        for (int i = 0; i < 8; i++) {
            const int tt = t0 + tb + i;
            const float dd = delta[tt * DI + d];
            cd += dd;
            const float u = dd * xs[tt * DI + d];
            const float4 B = *(const float4*)(Bm + tt * S + s0);
            h.x = __expf(dd * A.x) * h.x + u * B.x;
            h.y = __expf(dd * A.y) * h.y + u * B.y;
            h.z = __expf(dd * A.z) * h.z + u * B.z;
            h.w = __expf(dd * A.w) * h.w + u * B.w;
        }
    }
    *(float4*)(hloc + ((size_t)(c * DI + d)) * S + s0) = h;
    if (ln == 0) Dchunk[c * DI + d] = cd;
}

__global__ __launch_bounds__(256) void k3d_down(
    const float* __restrict__ A_log, const float* __restrict__ delta,
    const float* __restrict__ xs, const float* __restrict__ Bm,
    const float* __restrict__ Cm, const float* __restrict__ hloc,
    const float* __restrict__ Dchunk, float* __restrict__ y)
{
    const int tid = threadIdx.x;
    const int wv = tid >> 6, ln = tid & 63;
    const int d = blockIdx.x * 4 + wv;
    const int c = (NC - 1) - blockIdx.y;   // heavy carries first
    const int s0 = ln * 4;
    const int t0 = c * TCV;

    const float4 al = *(const float4*)(A_log + d * S + s0);
    float4 A;
    A.x = -__expf(al.x); A.y = -__expf(al.y);
    A.z = -__expf(al.z); A.w = -__expf(al.w);

    float4 h = make_float4(0.f, 0.f, 0.f, 0.f);
    for (int cp = 1; cp <= c; cp++) {
        const float4 hl = *(const float4*)(hloc + ((size_t)((cp - 1) * DI + d)) * S + s0);
        const float Dc = Dchunk[(cp - 1) * DI + d];
        h.x = hl.x + __expf(A.x * Dc) * h.x;
        h.y = hl.y + __expf(A.y * Dc) * h.y;
        h.z = hl.z + __expf(A.z * Dc) * h.z;
        h.w = hl.w + __expf(A.w * Dc) * h.w;
    }

    float pr[8];
    for (int tb = 0; tb < TCV; tb += 8) {
#pragma unroll
        for (int i = 0; i < 8; i++) {
            const int tt = t0 + tb + i;
            const float dd = delta[tt * DI + d];
            const float u = dd * xs[tt * DI + d];
            const float4 B = *(const float4*)(Bm + tt * S + s0);
            const float4 C = *(const float4*)(Cm + tt * S + s0);
            h.x = __expf(dd * A.x) * h.x + u * B.x;
            h.y = __expf(dd * A.y) * h.y + u * B.y;
            h.z = __expf(dd * A.z) * h.z + u * B.z;
            h.w = __expf(dd * A.w) * h.w + u * B.w;
            pr[i] = h.x * C.x + h.y * C.y + h.z * C.z + h.w * C.w;
        }

        float q0, q1, q2, q3;
        {
            const bool b0 = (ln & 1);
            float s_, r_;
            s_ = b0 ? pr[0] : pr[1]; r_ = __shfl_xor(s_, 1, 64);
            q0 = (b0 ? pr[1] : pr[0]) + r_;
            s_ = b0 ? pr[2] : pr[3]; r_ = __shfl_xor(s_, 1, 64);
            q1 = (b0 ? pr[3] : pr[2]) + r_;
            s_ = b0 ? pr[4] : pr[5]; r_ = __shfl_xor(s_, 1, 64);
            q2 = (b0 ? pr[5] : pr[4]) + r_;
            s_ = b0 ? pr[6] : pr[7]; r_ = __shfl_xor(s_, 1, 64);
            q3 = (b0 ? pr[7] : pr[6]) + r_;
        }
        {
            const bool b1 = (ln & 2);
            float s_, r_;
            s_ = b1 ? q0 : q1; r_ = __shfl_xor(s_, 2, 64);
            q0 = (b1 ? q1 : q0) + r_;
            s_ = b1 ? q2 : q3; r_ = __shfl_xor(s_, 2, 64);
            q1 = (b1 ? q3 : q2) + r_;
        }
        {
            const bool b2 = (ln & 4);
            const float s_ = b2 ? q0 : q1;
            const float r_ = __shfl_xor(s_, 4, 64);
            q0 = (b2 ? q1 : q0) + r_;
        }
        q0 += __shfl_xor(q0, 8, 64);
        q0 += __shfl_xor(q0, 16, 64);
        q0 += __shfl_xor(q0, 32, 64);
        if (ln < 8) y[(t0 + tb + ln) * DI + d] = q0;
    }
}

// ---------------------------------------------------------------------------
// K4: 256 blocks x 512 threads, 2 rows. feat split-K: 512 threads =
// 2 rows x 128 e x 2 c-halves; partials combined in LDS (lo+hi).
// ---------------------------------------------------------------------------
__global__ __launch_bounds__(512) void k4_heads(
    const float* __restrict__ y, const float* __restrict__ xs,
    const float* __restrict__ Dp, const float* __restrict__ zg,
    const float* __restrict__ W_out,
    const float* __restrict__ We, const float* __restrict__ be,
    const float* __restrict__ Wa, const float* __restrict__ ba,
    const float* __restrict__ Wq, const float* __restrict__ bq,
    float* __restrict__ out)
{
    const int bb = blockIdx.x * 2;
    const int tid = threadIdx.x;
    __shared__ float yf[2][DI];
    __shared__ float fpart[2][2][E];     // [half][r][e]
    __shared__ float feat[2][E];

    for (int idx = tid; idx < 2 * DI; idx += 512) {
        const int r = idx >> 8, c = idx & 255;
        const int b = bb + r;
        const float z = zg[b * DI + c];
        yf[r][c] = (y[b * DI + c] + xs[b * DI + c] * Dp[c]) * silu_f(z);
    }
    __syncthreads();

    {
        const int hf = tid >> 8;         // 0/1: c-half
        const int r  = (tid >> 7) & 1;
        const int e  = tid & 127;
        const float4* wr = (const float4*)(W_out + (size_t)e * DI) + hf * 32;
        const float4* yv = (const float4*)yf[r] + hf * 32;
        float a = 0.0f;
#pragma unroll 8
        for (int d4 = 0; d4 < 32; d4++) {
            const float4 w = wr[d4];
            const float4 v = yv[d4];
            a += v.x * w.x; a += v.y * w.y; a += v.z * w.z; a += v.w * w.w;
        }
        fpart[hf][r][e] = a;
    }
    __syncthreads();

    if (tid < 256) {
        const int r = tid >> 7, e = tid & 127;
        feat[r][e] = fpart[0][r][e] + fpart[1][r][e];
    }
    __syncthreads();

    if (tid < 16) {
        const int r = tid >> 3, hd = tid & 7;
        const int b = bb + r;
        const float* wrow;
        float bias;
        int dst;
        if (hd == 0)      { wrow = We;                 bias = be[0];      dst = b; }
        else if (hd < 4)  { wrow = Wa + (hd - 1) * E;  bias = ba[hd - 1]; dst = 512 + b * 3 + (hd - 1); }
        else              { wrow = Wq + (hd - 4) * E;  bias = bq[hd - 4]; dst = 2048 + b * 4 + (hd - 4); }
        float a = bias;
#pragma unroll 4
        for (int e = 0; e < E; e++) a += feat[r][e] * wrow[e];
        out[dst] = a;
    }
}

// ===========================================================================
extern "C" void kernel_launch(void* const* d_in, const int* in_sizes, int n_in,
                              void* d_out, int out_size, void* d_ws, size_t ws_size,
                              hipStream_t stream)
{
    const float* x        = (const float*)d_in[0];
    const float* conv_w   = (const float*)d_in[1];
    const float* conv_b   = (const float*)d_in[2];
    const float* lin_w    = (const float*)d_in[3];
    const float* lin_b    = (const float*)d_in[4];
    const float* W_in     = (const float*)d_in[5];
    const float* conv1d_w = (const float*)d_in[6];
    const float* conv1d_b = (const float*)d_in[7];
    const float* W_x      = (const float*)d_in[8];
    const float* W_dt     = (const float*)d_in[9];
    const float* b_dt     = (const float*)d_in[10];
    const float* A_log    = (const float*)d_in[11];
    const float* Dp       = (const float*)d_in[12];
    const float* W_out    = (const float*)d_in[13];
    const float* We       = (const float*)d_in[14];
    const float* be       = (const float*)d_in[15];
    const float* Wa       = (const float*)d_in[16];
    const float* ba       = (const float*)d_in[17];
    const float* Wq       = (const float*)d_in[18];
    const float* bq       = (const float*)d_in[19];
    float* out = (float*)d_out;

    float* ws = (float*)d_ws;
    float* xm     = ws;                    // 512*256 each below
    float* zg     = xm     + 512 * 256;
    float* xs     = zg     + 512 * 256;
    float* delta  = xs     + 512 * 256;
    float* Bm     = delta  + 512 * 256;
    float* Cm     = Bm     + 512 * 256;
    float* y      = Cm     + 512 * 256;
    float* hloc   = y      + 512 * 256;    // NC*DI*S
    float* Dchunk = hloc   + (size_t)NC * DI * S;   // NC*DI

    kA_pre<<<256, 512, 0, stream>>>(x, conv_w, conv_b, lin_w, lin_b, W_in,
                                    xm, zg);
    k2b_conv_wx<<<dim3(128, 2), 512, 0, stream>>>(xm, conv1d_w, conv1d_b, W_x,
                                                  W_dt, b_dt, xs, delta, Bm, Cm);
    k3u_up<<<dim3(64, NC - 1), 256, 0, stream>>>(A_log, delta, xs, Bm, hloc, Dchunk);
    k3d_down<<<dim3(64, NC), 256, 0, stream>>>(A_log, delta, xs, Bm, Cm,
                                               hloc, Dchunk, y);
    k4_heads<<<256, 512, 0, stream>>>(y, xs, Dp, zg, W_out, We, be, Wa, ba, Wq, bq, out);
}